// Round 22
// baseline (267.699 us; speedup 1.0000x reference)
//
#include <hip/hip_runtime.h>

#define DEV_INLINE __device__ __forceinline__

constexpr int NF = 26;   // input features
constexpr int H1 = 24;   // layer-1 hidden
constexpr int H2 = 8;    // layer-2 hidden
constexpr int T  = 5;    // sequence length
constexpr int BPW  = 32; // batch rows per wave (2 M-tiles of 16)
constexpr int ROWU = 20; // uints per LDS h-row (40 f16 = 80 B)

constexpr float L2E     = 1.44269504088896f;   // log2(e)
constexpr float TWO_L2E = 2.88539008177792f;   // 2*log2(e)

typedef _Float16 f16x8 __attribute__((ext_vector_type(8)));
typedef float    f32x4 __attribute__((ext_vector_type(4)));
typedef __fp16   fp16x2 __attribute__((ext_vector_type(2)));

union Q { uint4 u; f16x8 h; };

DEV_INLINE float fast_rcp(float x) { return __builtin_amdgcn_rcpf(x); }
// 1/(1+2^-x); with pre-scaled gate a = log2e*raw this IS sigmoid(raw).
DEV_INLINE float rcp1p(float x) { return fast_rcp(1.0f + __builtin_amdgcn_exp2f(-x)); }
// cell with PRE-SCALED gates: i,f,o scaled by log2e; g scaled by 2*log2e.
DEV_INLINE float cellp(float i_, float f_, float g_, float o_, float& c) {
    const float ig = rcp1p(i_), fg = rcp1p(f_);
    const float gg = fmaf(2.0f, rcp1p(g_), -1.0f);   // tanh(raw g)
    const float og = rcp1p(o_);
    c = fmaf(fg, c, ig * gg);
    return og * fmaf(2.0f, rcp1p(c * TWO_L2E), -1.0f);   // o*tanh(c)
}
DEV_INLINE uint pkrtz(float a, float b) {
    union { uint u; fp16x2 p; } v; v.p = __builtin_amdgcn_cvt_pkrtz(a, b); return v.u;
}
// lane^8 exchange via DPP row_ror:8 (ctrl 0x128): (i+8) mod 16 == i^8 within
// each 16-lane row. VALU pipe, zero LDS occupancy. CONVERGENT: all lanes.
DEV_INLINE float swz8(float v) {
    union { float f; int i; } a, b;
    a.f = v;
    b.i = __builtin_amdgcn_mov_dpp(a.i, 0x128, 0xf, 0xf, true);
    return b.f;
}

// R22 = R20 with ALL in-loop sched_barrier(0) fences REMOVED.
// Those fences were register-pressure control from the R13 era (live set ~150
// at a 170 cap). Today: 48 arch + 32 acc = 80 regs under the (256,5) 102 cap.
// The fences only forbid cross-phase overlap now (~35% idle issue slots).
// LDS ordering is preserved by the compiler's memory-dependence analysis and
// the in-order DS pipe; the DPP exchange is unconditional (convergent).
// Tripwire: if the freed scheduler spills, WRITE_SIZE >> 8.2 MB -> revert R20.

__global__ __launch_bounds__(256, 5) void lstm2_mfma(
    const float* __restrict__ x,
    const float* __restrict__ w_ih1, const float* __restrict__ w_hh1,
    const float* __restrict__ b_ih1, const float* __restrict__ b_hh1,
    const float* __restrict__ w_ih2, const float* __restrict__ w_hh2,
    const float* __restrict__ b_ih2, const float* __restrict__ b_hh2,
    float* __restrict__ out, int batch)
{
    __shared__ uint4 sW[20][64];         // 20 KiB: weight B-fragments
    __shared__ uint  sH[4][BPW * ROWU];  // 10 KiB: [h1|h2] f16 state, wave-private
    __shared__ float sB1[8 * 16];        // pre-scaled (b_ih1+b_hh1), [tau][j16]
    __shared__ float sB2[4 * 16];        // pre-scaled (b_ih2+b_hh2), [t2][j16]

    const int tid = threadIdx.x;
    const int w   = tid >> 6;        // wave id
    const int l   = tid & 63;        // lane
    const int q   = l >> 4;          // quarter (k-slice 8q..8q+7)
    const int r16 = l & 15;          // row (A) / col (B,C) within 16x16 tile
    const bool lo = (r16 < 8);
    const int wb  = blockIdx.x * 128 + w * BPW;

    // ---- zero sH (h=0 init); wave-private ----
    for (int i = l; i < BPW * ROWU; i += 64) sH[w][i] = 0u;

    // ---- x pointers (clamped rows) ----
    int row0 = wb + r16;      if (row0 > batch - 1) row0 = batch - 1;
    int row1 = wb + 16 + r16; if (row1 > batch - 1) row1 = batch - 1;
    const float* __restrict__ xp0 = x + (size_t)row0 * (T * NF) + q * 8;
    const float* __restrict__ xp1 = x + (size_t)row1 * (T * NF) + q * 8;
    const bool q3 = (q == 3);
    const float2 z2 = make_float2(0.0f, 0.0f);

    // ---- cooperative weight staging (pre-scaled): wave w does tiles w,w+4,.. ----
    for (int tile = w; tile < 20; tile += 4) {
        f16x8 bf;
        if (tile < 16) {
            const int tau  = tile & 7;
            const int gate = tau >> 1, j = (tau & 1) * 16 + r16;
            const bool jv  = (j < H1);
            const int row  = gate * H1 + (jv ? j : 0);
            const bool ih  = (tile < 8);
            const float sc = (gate == 2) ? TWO_L2E : L2E;
            #pragma unroll
            for (int e = 0; e < 8; ++e) {
                const int k = q * 8 + e;
                float v = 0.0f;
                if (ih) { if (jv && k < NF) v = w_ih1[row * NF + k]; }
                else    { if (jv && k < H1) v = w_hh1[row * H1 + k]; }
                bf[e] = (_Float16)(v * sc);
            }
        } else {
            const int t2  = tile - 16;
            const bool jv = (r16 < H2);
            const int row = t2 * H2 + (jv ? r16 : 0);
            const float sc = (t2 == 2) ? TWO_L2E : L2E;
            #pragma unroll
            for (int e = 0; e < 8; ++e) {
                const int k = q * 8 + e;
                float v = 0.0f;
                if (jv) v = (k < H1) ? w_ih2[row * H1 + k] : w_hh2[row * H2 + (k - H1)];
                bf[e] = (_Float16)(v * sc);
            }
        }
        Q u; u.h = bf;
        sW[tile][l] = u.u;
    }

    // ---- biases -> LDS (pre-scaled) ----
    if (tid < 128) {
        const int tau = tid >> 4, col = tid & 15;
        const int gate = tau >> 1, j = (tau & 1) * 16 + col;
        const bool jv = (j < H1);
        const int row = gate * H1 + (jv ? j : 0);
        const float sc = (gate == 2) ? TWO_L2E : L2E;
        sB1[tid] = jv ? (b_ih1[row] + b_hh1[row]) * sc : 0.0f;
    } else if (tid < 192) {
        const int idx = tid - 128;
        const int t2 = idx >> 4, col = idx & 15;
        const bool jv = (col < H2);
        const int row = t2 * H2 + (jv ? col : 0);
        const float sc = (t2 == 2) ? TWO_L2E : L2E;
        sB2[idx] = jv ? (b_ih2[row] + b_hh2[row]) * sc : 0.0f;
    }

    __syncthreads();   // weights+biases visible (only barrier in kernel)

    // c-state: even half per-m (all lanes); merged halves per-lane single m
    float c1a[2][4] = {}, c1b[4] = {}, c2s[4] = {};
    const uint4* HQ = reinterpret_cast<const uint4*>(&sH[w][0]);
    _Float16*   Hh  = reinterpret_cast<_Float16*>(&sH[w][0]);

    #pragma unroll 1
    for (int t = 0; t < T; ++t) {
        // ---- JIT x load + convert ----
        Q xa[2];
        #pragma unroll
        for (int m = 0; m < 2; ++m) {
            const float* __restrict__ p = (m ? xp1 : xp0) + t * NF;
            float2 v0 = *reinterpret_cast<const float2*>(p);
            float2 v1 = q3 ? z2 : *reinterpret_cast<const float2*>(p + 2);
            float2 v2 = q3 ? z2 : *reinterpret_cast<const float2*>(p + 4);
            float2 v3 = q3 ? z2 : *reinterpret_cast<const float2*>(p + 6);
            uint4 u;
            u.x = pkrtz(v0.x, v0.y);
            u.y = pkrtz(v1.x, v1.y);
            u.z = pkrtz(v2.x, v2.y);
            u.w = pkrtz(v3.x, v3.y);
            xa[m].u = u;
        }

        // ---- read [h1|h2](prev t) A-frags ----
        Q ha[2];
        #pragma unroll
        for (int m = 0; m < 2; ++m) ha[m].u = HQ[(m * 16 + r16) * 5 + q];

        f32x4 acc[2][4];                     // one block reused by all phases

        // ---- layer 1, even half (cols j=r16, full lanes, per-m cells) ----
        #pragma unroll
        for (int g = 0; g < 4; ++g) {
            const float b = sB1[(2 * g) * 16 + r16];
            f32x4 bv = {b, b, b, b};
            acc[0][g] = bv;
            acc[1][g] = bv;
        }
        #pragma unroll
        for (int g = 0; g < 4; ++g) {
            const int tau = 2 * g;
            Q wi, wh;
            wi.u = sW[tau][l];
            wh.u = sW[8 + tau][l];
            acc[0][g] = __builtin_amdgcn_mfma_f32_16x16x32_f16(xa[0].h, wi.h, acc[0][g], 0, 0, 0);
            acc[1][g] = __builtin_amdgcn_mfma_f32_16x16x32_f16(xa[1].h, wi.h, acc[1][g], 0, 0, 0);
            acc[0][g] = __builtin_amdgcn_mfma_f32_16x16x32_f16(ha[0].h, wh.h, acc[0][g], 0, 0, 0);
            acc[1][g] = __builtin_amdgcn_mfma_f32_16x16x32_f16(ha[1].h, wh.h, acc[1][g], 0, 0, 0);
        }
        #pragma unroll
        for (int m = 0; m < 2; ++m) {
            #pragma unroll
            for (int r = 0; r < 4; ++r) {
                const int lrow = m * 16 + q * 4 + r;        // C row = 4*(l>>4)+reg
                const float hv = cellp(acc[m][0][r], acc[m][1][r], acc[m][2][r], acc[m][3][r], c1a[m][r]);
                Hh[lrow * 40 + r16] = (_Float16)hv;         // col j = r16
            }
        }

        // ---- layer 1, odd half (cols 16..23): MERGED across m (full lanes) ----
        #pragma unroll
        for (int g = 0; g < 4; ++g) {
            const float b = sB1[(2 * g + 1) * 16 + r16];
            f32x4 bv = {b, b, b, b};
            acc[0][g] = bv;
            acc[1][g] = bv;
        }
        #pragma unroll
        for (int g = 0; g < 4; ++g) {
            const int tau = 2 * g + 1;
            Q wi, wh;
            wi.u = sW[tau][l];
            wh.u = sW[8 + tau][l];
            acc[0][g] = __builtin_amdgcn_mfma_f32_16x16x32_f16(xa[0].h, wi.h, acc[0][g], 0, 0, 0);
            acc[1][g] = __builtin_amdgcn_mfma_f32_16x16x32_f16(xa[1].h, wi.h, acc[1][g], 0, 0, 0);
            acc[0][g] = __builtin_amdgcn_mfma_f32_16x16x32_f16(ha[0].h, wh.h, acc[0][g], 0, 0, 0);
            acc[1][g] = __builtin_amdgcn_mfma_f32_16x16x32_f16(ha[1].h, wh.h, acc[1][g], 0, 0, 0);
        }
        #pragma unroll
        for (int r = 0; r < 4; ++r) {
            // ALL lanes run the DPP exchange (convergent); select afterwards.
            const float si = swz8(acc[1][0][r]);
            const float sf = swz8(acc[1][1][r]);
            const float sg = swz8(acc[1][2][r]);
            const float so = swz8(acc[1][3][r]);
            const float i_ = lo ? acc[0][0][r] : si;
            const float f_ = lo ? acc[0][1][r] : sf;
            const float g_ = lo ? acc[0][2][r] : sg;
            const float o_ = lo ? acc[0][3][r] : so;
            const float hv = cellp(i_, f_, g_, o_, c1b[r]);
            const int lrow = (lo ? 0 : 16) + q * 4 + r;
            Hh[lrow * 40 + 16 + (r16 & 7)] = (_Float16)hv;
        }

        // ---- layer 2: A = [h1(t) | h2(t-1)]; cells MERGED across m ----
        Q hc[2];
        #pragma unroll
        for (int m = 0; m < 2; ++m) hc[m].u = HQ[(m * 16 + r16) * 5 + q];
        #pragma unroll
        for (int t2 = 0; t2 < 4; ++t2) {
            const float b = sB2[t2 * 16 + r16];
            f32x4 bv = {b, b, b, b};
            acc[0][t2] = bv;
            acc[1][t2] = bv;
        }
        #pragma unroll
        for (int t2 = 0; t2 < 4; ++t2) {
            Q wc; wc.u = sW[16 + t2][l];
            acc[0][t2] = __builtin_amdgcn_mfma_f32_16x16x32_f16(hc[0].h, wc.h, acc[0][t2], 0, 0, 0);
            acc[1][t2] = __builtin_amdgcn_mfma_f32_16x16x32_f16(hc[1].h, wc.h, acc[1][t2], 0, 0, 0);
        }
        #pragma unroll
        for (int r = 0; r < 4; ++r) {
            const float si = swz8(acc[1][0][r]);
            const float sf = swz8(acc[1][1][r]);
            const float sg = swz8(acc[1][2][r]);
            const float so = swz8(acc[1][3][r]);
            const float i_ = lo ? acc[0][0][r] : si;
            const float f_ = lo ? acc[0][1][r] : sf;
            const float g_ = lo ? acc[0][2][r] : sg;
            const float o_ = lo ? acc[0][3][r] : so;
            const float h2v = cellp(i_, f_, g_, o_, c2s[r]);
            const int lrow = (lo ? 0 : 16) + q * 4 + r;
            Hh[lrow * 40 + 24 + (r16 & 7)] = (_Float16)h2v;   // h2 cols 24..31
        }
    }

    // ---- epilogue: read final h2 from sH, coalesced float4 out ----
    {
        const int erow = l >> 1, ecg = l & 1;
        const uint2 hv = *reinterpret_cast<const uint2*>(&Hh[erow * 40 + 24 + ecg * 4]);
        union { uint u; fp16x2 p; } a0, a1;
        a0.u = hv.x; a1.u = hv.y;
        const int orow = wb + erow;
        if (orow < batch) {
            float4 o = make_float4((float)a0.p[0], (float)a0.p[1],
                                   (float)a1.p[0], (float)a1.p[1]);
            *reinterpret_cast<float4*>(out + (size_t)orow * H2 + ecg * 4) = o;
        }
    }
}

extern "C" void kernel_launch(void* const* d_in, const int* in_sizes, int n_in,
                              void* d_out, int out_size, void* d_ws, size_t ws_size,
                              hipStream_t stream)
{
    const float* x     = (const float*)d_in[0];
    const float* w_ih1 = (const float*)d_in[1];
    const float* w_hh1 = (const float*)d_in[2];
    const float* b_ih1 = (const float*)d_in[3];
    const float* b_hh1 = (const float*)d_in[4];
    const float* w_ih2 = (const float*)d_in[5];
    const float* w_hh2 = (const float*)d_in[6];
    const float* b_ih2 = (const float*)d_in[7];
    const float* b_hh2 = (const float*)d_in[8];
    float* out = (float*)d_out;

    const int batch = in_sizes[0] / (T * NF);
    const int block = 256;                    // 4 waves x 32 batch rows
    const int grid  = (batch + 127) / 128;
    lstm2_mfma<<<grid, block, 0, stream>>>(x, w_ih1, w_hh1, b_ih1, b_hh1,
                                           w_ih2, w_hh2, b_ih2, b_hh2,
                                           out, batch);
}

// Round 23
// 72.147 us; speedup vs baseline: 3.7104x; 3.7104x over previous
//
#include <hip/hip_runtime.h>

#define DEV_INLINE __device__ __forceinline__

constexpr int NF = 26;   // input features
constexpr int H1 = 24;   // layer-1 hidden
constexpr int H2 = 8;    // layer-2 hidden
constexpr int T  = 5;    // sequence length
constexpr int BPW  = 32; // batch rows per wave (2 M-tiles of 16)
constexpr int ROWU = 20; // uints per LDS h-row (40 f16 = 80 B)

constexpr float L2E     = 1.44269504088896f;   // log2(e)
constexpr float TWO_L2E = 2.88539008177792f;   // 2*log2(e)

typedef _Float16 f16x8 __attribute__((ext_vector_type(8)));
typedef float    f32x4 __attribute__((ext_vector_type(4)));
typedef __fp16   fp16x2 __attribute__((ext_vector_type(2)));

union Q { uint4 u; f16x8 h; };

DEV_INLINE float fast_rcp(float x) { return __builtin_amdgcn_rcpf(x); }
// 1/(1+2^-x); with pre-scaled gate a = log2e*raw this IS sigmoid(raw).
DEV_INLINE float rcp1p(float x) { return fast_rcp(1.0f + __builtin_amdgcn_exp2f(-x)); }
// cell with PRE-SCALED gates: i,f,o scaled by log2e; g scaled by 2*log2e.
DEV_INLINE float cellp(float i_, float f_, float g_, float o_, float& c) {
    const float ig = rcp1p(i_), fg = rcp1p(f_);
    const float gg = fmaf(2.0f, rcp1p(g_), -1.0f);   // tanh(raw g)
    const float og = rcp1p(o_);
    c = fmaf(fg, c, ig * gg);
    return og * fmaf(2.0f, rcp1p(c * TWO_L2E), -1.0f);   // o*tanh(c)
}
DEV_INLINE uint pkrtz(float a, float b) {
    union { uint u; fp16x2 p; } v; v.p = __builtin_amdgcn_cvt_pkrtz(a, b); return v.u;
}
// lane^8 exchange via DPP row_ror:8 (ctrl 0x128): (i+8) mod 16 == i^8 within
// each 16-lane row. VALU pipe, zero LDS occupancy. CONVERGENT: all lanes.
DEV_INLINE float swz8(float v) {
    union { float f; int i; } a, b;
    a.f = v;
    b.i = __builtin_amdgcn_mov_dpp(a.i, 0x128, 0xf, 0xf, true);
    return b.f;
}

// R23 = R20 verbatim (champion, 72.3 us). R22 proved the per-phase
// sched_barrier(0) fences are the register allocator's contract: without them
// the scheduler merges all phases, spills (~700 MB scratch), 267 us. The
// ~35% idle-issue gap is the price of the 80-reg fit; all levers to buy it
// back (R18 waves, R19/R21 prefetch, R22 fences) measured neutral-to-negative.
//  * merged full-lane cells via DPP row_ror:8 (convergent, off LDS pipe)
//  * log2e pre-scaled weights/biases; exp2-based cells
//  * sW block-shared (staged once), sH wave-private, no __syncthreads in t-loop

__global__ __launch_bounds__(256, 5) void lstm2_mfma(
    const float* __restrict__ x,
    const float* __restrict__ w_ih1, const float* __restrict__ w_hh1,
    const float* __restrict__ b_ih1, const float* __restrict__ b_hh1,
    const float* __restrict__ w_ih2, const float* __restrict__ w_hh2,
    const float* __restrict__ b_ih2, const float* __restrict__ b_hh2,
    float* __restrict__ out, int batch)
{
    __shared__ uint4 sW[20][64];         // 20 KiB: weight B-fragments
    __shared__ uint  sH[4][BPW * ROWU];  // 10 KiB: [h1|h2] f16 state, wave-private
    __shared__ float sB1[8 * 16];        // pre-scaled (b_ih1+b_hh1), [tau][j16]
    __shared__ float sB2[4 * 16];        // pre-scaled (b_ih2+b_hh2), [t2][j16]

    const int tid = threadIdx.x;
    const int w   = tid >> 6;        // wave id
    const int l   = tid & 63;        // lane
    const int q   = l >> 4;          // quarter (k-slice 8q..8q+7)
    const int r16 = l & 15;          // row (A) / col (B,C) within 16x16 tile
    const bool lo = (r16 < 8);
    const int wb  = blockIdx.x * 128 + w * BPW;

    // ---- zero sH (h=0 init); wave-private ----
    for (int i = l; i < BPW * ROWU; i += 64) sH[w][i] = 0u;

    // ---- x pointers (clamped rows) ----
    int row0 = wb + r16;      if (row0 > batch - 1) row0 = batch - 1;
    int row1 = wb + 16 + r16; if (row1 > batch - 1) row1 = batch - 1;
    const float* __restrict__ xp0 = x + (size_t)row0 * (T * NF) + q * 8;
    const float* __restrict__ xp1 = x + (size_t)row1 * (T * NF) + q * 8;
    const bool q3 = (q == 3);
    const float2 z2 = make_float2(0.0f, 0.0f);

    // ---- cooperative weight staging (pre-scaled): wave w does tiles w,w+4,.. ----
    for (int tile = w; tile < 20; tile += 4) {
        f16x8 bf;
        if (tile < 16) {
            const int tau  = tile & 7;
            const int gate = tau >> 1, j = (tau & 1) * 16 + r16;
            const bool jv  = (j < H1);
            const int row  = gate * H1 + (jv ? j : 0);
            const bool ih  = (tile < 8);
            const float sc = (gate == 2) ? TWO_L2E : L2E;
            #pragma unroll
            for (int e = 0; e < 8; ++e) {
                const int k = q * 8 + e;
                float v = 0.0f;
                if (ih) { if (jv && k < NF) v = w_ih1[row * NF + k]; }
                else    { if (jv && k < H1) v = w_hh1[row * H1 + k]; }
                bf[e] = (_Float16)(v * sc);
            }
        } else {
            const int t2  = tile - 16;
            const bool jv = (r16 < H2);
            const int row = t2 * H2 + (jv ? r16 : 0);
            const float sc = (t2 == 2) ? TWO_L2E : L2E;
            #pragma unroll
            for (int e = 0; e < 8; ++e) {
                const int k = q * 8 + e;
                float v = 0.0f;
                if (jv) v = (k < H1) ? w_ih2[row * H1 + k] : w_hh2[row * H2 + (k - H1)];
                bf[e] = (_Float16)(v * sc);
            }
        }
        Q u; u.h = bf;
        sW[tile][l] = u.u;
    }

    // ---- biases -> LDS (pre-scaled) ----
    if (tid < 128) {
        const int tau = tid >> 4, col = tid & 15;
        const int gate = tau >> 1, j = (tau & 1) * 16 + col;
        const bool jv = (j < H1);
        const int row = gate * H1 + (jv ? j : 0);
        const float sc = (gate == 2) ? TWO_L2E : L2E;
        sB1[tid] = jv ? (b_ih1[row] + b_hh1[row]) * sc : 0.0f;
    } else if (tid < 192) {
        const int idx = tid - 128;
        const int t2 = idx >> 4, col = idx & 15;
        const bool jv = (col < H2);
        const int row = t2 * H2 + (jv ? col : 0);
        const float sc = (t2 == 2) ? TWO_L2E : L2E;
        sB2[idx] = jv ? (b_ih2[row] + b_hh2[row]) * sc : 0.0f;
    }

    __syncthreads();   // weights+biases visible (only barrier in kernel)

    // c-state: even half per-m (all lanes); merged halves per-lane single m
    float c1a[2][4] = {}, c1b[4] = {}, c2s[4] = {};
    const uint4* HQ = reinterpret_cast<const uint4*>(&sH[w][0]);
    _Float16*   Hh  = reinterpret_cast<_Float16*>(&sH[w][0]);

    #pragma unroll 1
    for (int t = 0; t < T; ++t) {
        // ---- JIT x load + convert ----
        Q xa[2];
        #pragma unroll
        for (int m = 0; m < 2; ++m) {
            const float* __restrict__ p = (m ? xp1 : xp0) + t * NF;
            float2 v0 = *reinterpret_cast<const float2*>(p);
            float2 v1 = q3 ? z2 : *reinterpret_cast<const float2*>(p + 2);
            float2 v2 = q3 ? z2 : *reinterpret_cast<const float2*>(p + 4);
            float2 v3 = q3 ? z2 : *reinterpret_cast<const float2*>(p + 6);
            uint4 u;
            u.x = pkrtz(v0.x, v0.y);
            u.y = pkrtz(v1.x, v1.y);
            u.z = pkrtz(v2.x, v2.y);
            u.w = pkrtz(v3.x, v3.y);
            xa[m].u = u;
        }

        // ---- read [h1|h2](prev t) A-frags ----
        Q ha[2];
        #pragma unroll
        for (int m = 0; m < 2; ++m) ha[m].u = HQ[(m * 16 + r16) * 5 + q];
        __builtin_amdgcn_sched_barrier(0);   // frag reads before h1 overwrite (WAR)

        f32x4 acc[2][4];                     // one block reused by all phases

        // ---- layer 1, even half (cols j=r16, full lanes, per-m cells) ----
        #pragma unroll
        for (int g = 0; g < 4; ++g) {
            const float b = sB1[(2 * g) * 16 + r16];
            f32x4 bv = {b, b, b, b};
            acc[0][g] = bv;
            acc[1][g] = bv;
        }
        #pragma unroll
        for (int g = 0; g < 4; ++g) {
            const int tau = 2 * g;
            Q wi, wh;
            wi.u = sW[tau][l];
            wh.u = sW[8 + tau][l];
            acc[0][g] = __builtin_amdgcn_mfma_f32_16x16x32_f16(xa[0].h, wi.h, acc[0][g], 0, 0, 0);
            acc[1][g] = __builtin_amdgcn_mfma_f32_16x16x32_f16(xa[1].h, wi.h, acc[1][g], 0, 0, 0);
            acc[0][g] = __builtin_amdgcn_mfma_f32_16x16x32_f16(ha[0].h, wh.h, acc[0][g], 0, 0, 0);
            acc[1][g] = __builtin_amdgcn_mfma_f32_16x16x32_f16(ha[1].h, wh.h, acc[1][g], 0, 0, 0);
            if (g == 1) __builtin_amdgcn_sched_barrier(0);  // cap frag window
        }
        __builtin_amdgcn_sched_barrier(0);
        #pragma unroll
        for (int m = 0; m < 2; ++m) {
            #pragma unroll
            for (int r = 0; r < 4; ++r) {
                const int lrow = m * 16 + q * 4 + r;        // C row = 4*(l>>4)+reg
                const float hv = cellp(acc[m][0][r], acc[m][1][r], acc[m][2][r], acc[m][3][r], c1a[m][r]);
                Hh[lrow * 40 + r16] = (_Float16)hv;         // col j = r16
            }
        }
        __builtin_amdgcn_sched_barrier(0);

        // ---- layer 1, odd half (cols 16..23): MERGED across m (full lanes) ----
        #pragma unroll
        for (int g = 0; g < 4; ++g) {
            const float b = sB1[(2 * g + 1) * 16 + r16];
            f32x4 bv = {b, b, b, b};
            acc[0][g] = bv;
            acc[1][g] = bv;
        }
        #pragma unroll
        for (int g = 0; g < 4; ++g) {
            const int tau = 2 * g + 1;
            Q wi, wh;
            wi.u = sW[tau][l];
            wh.u = sW[8 + tau][l];
            acc[0][g] = __builtin_amdgcn_mfma_f32_16x16x32_f16(xa[0].h, wi.h, acc[0][g], 0, 0, 0);
            acc[1][g] = __builtin_amdgcn_mfma_f32_16x16x32_f16(xa[1].h, wi.h, acc[1][g], 0, 0, 0);
            acc[0][g] = __builtin_amdgcn_mfma_f32_16x16x32_f16(ha[0].h, wh.h, acc[0][g], 0, 0, 0);
            acc[1][g] = __builtin_amdgcn_mfma_f32_16x16x32_f16(ha[1].h, wh.h, acc[1][g], 0, 0, 0);
            if (g == 1) __builtin_amdgcn_sched_barrier(0);
        }
        __builtin_amdgcn_sched_barrier(0);
        #pragma unroll
        for (int r = 0; r < 4; ++r) {
            // ALL lanes run the DPP exchange (convergent); select afterwards.
            const float si = swz8(acc[1][0][r]);
            const float sf = swz8(acc[1][1][r]);
            const float sg = swz8(acc[1][2][r]);
            const float so = swz8(acc[1][3][r]);
            const float i_ = lo ? acc[0][0][r] : si;
            const float f_ = lo ? acc[0][1][r] : sf;
            const float g_ = lo ? acc[0][2][r] : sg;
            const float o_ = lo ? acc[0][3][r] : so;
            const float hv = cellp(i_, f_, g_, o_, c1b[r]);
            const int lrow = (lo ? 0 : 16) + q * 4 + r;
            Hh[lrow * 40 + 16 + (r16 & 7)] = (_Float16)hv;
        }
        __builtin_amdgcn_sched_barrier(0);   // h1 writes before hc reads (RAW)

        // ---- layer 2: A = [h1(t) | h2(t-1)]; cells MERGED across m ----
        Q hc[2];
        #pragma unroll
        for (int m = 0; m < 2; ++m) hc[m].u = HQ[(m * 16 + r16) * 5 + q];
        __builtin_amdgcn_sched_barrier(0);   // hc reads before h2 overwrite (WAR)
        #pragma unroll
        for (int t2 = 0; t2 < 4; ++t2) {
            const float b = sB2[t2 * 16 + r16];
            f32x4 bv = {b, b, b, b};
            acc[0][t2] = bv;
            acc[1][t2] = bv;
        }
        #pragma unroll
        for (int t2 = 0; t2 < 4; ++t2) {
            Q wc; wc.u = sW[16 + t2][l];
            acc[0][t2] = __builtin_amdgcn_mfma_f32_16x16x32_f16(hc[0].h, wc.h, acc[0][t2], 0, 0, 0);
            acc[1][t2] = __builtin_amdgcn_mfma_f32_16x16x32_f16(hc[1].h, wc.h, acc[1][t2], 0, 0, 0);
        }
        __builtin_amdgcn_sched_barrier(0);
        #pragma unroll
        for (int r = 0; r < 4; ++r) {
            const float si = swz8(acc[1][0][r]);
            const float sf = swz8(acc[1][1][r]);
            const float sg = swz8(acc[1][2][r]);
            const float so = swz8(acc[1][3][r]);
            const float i_ = lo ? acc[0][0][r] : si;
            const float f_ = lo ? acc[0][1][r] : sf;
            const float g_ = lo ? acc[0][2][r] : sg;
            const float o_ = lo ? acc[0][3][r] : so;
            const float h2v = cellp(i_, f_, g_, o_, c2s[r]);
            const int lrow = (lo ? 0 : 16) + q * 4 + r;
            Hh[lrow * 40 + 24 + (r16 & 7)] = (_Float16)h2v;   // h2 cols 24..31
        }
        __builtin_amdgcn_sched_barrier(0);   // h2 writes before next-t ha reads (RAW)
    }

    // ---- epilogue: read final h2 from sH, coalesced float4 out ----
    {
        const int erow = l >> 1, ecg = l & 1;
        const uint2 hv = *reinterpret_cast<const uint2*>(&Hh[erow * 40 + 24 + ecg * 4]);
        union { uint u; fp16x2 p; } a0, a1;
        a0.u = hv.x; a1.u = hv.y;
        const int orow = wb + erow;
        if (orow < batch) {
            float4 o = make_float4((float)a0.p[0], (float)a0.p[1],
                                   (float)a1.p[0], (float)a1.p[1]);
            *reinterpret_cast<float4*>(out + (size_t)orow * H2 + ecg * 4) = o;
        }
    }
}

extern "C" void kernel_launch(void* const* d_in, const int* in_sizes, int n_in,
                              void* d_out, int out_size, void* d_ws, size_t ws_size,
                              hipStream_t stream)
{
    const float* x     = (const float*)d_in[0];
    const float* w_ih1 = (const float*)d_in[1];
    const float* w_hh1 = (const float*)d_in[2];
    const float* b_ih1 = (const float*)d_in[3];
    const float* b_hh1 = (const float*)d_in[4];
    const float* w_ih2 = (const float*)d_in[5];
    const float* w_hh2 = (const float*)d_in[6];
    const float* b_ih2 = (const float*)d_in[7];
    const float* b_hh2 = (const float*)d_in[8];
    float* out = (float*)d_out;

    const int batch = in_sizes[0] / (T * NF);
    const int block = 256;                    // 4 waves x 32 batch rows
    const int grid  = (batch + 127) / 128;
    lstm2_mfma<<<grid, block, 0, stream>>>(x, w_ih1, w_hh1, b_ih1, b_hh1,
                                           w_ih2, w_hh2, b_ih2, b_hh2,
                                           out, batch);
}